// Round 1
// baseline (1193.885 us; speedup 1.0000x reference)
//
#include <hip/hip_runtime.h>
#include <hip/hip_bf16.h>
#include <cstdint>

// MultiViewGAT: N=8192, F=128.
// Assumptions (round 1): all float inputs are fp32 (reference says jnp.float32),
// adjs (bool in reference) arrives as int32 0/1 per harness "integer -> const int*",
// output is fp32.
// Math note: scores are rank-1 (f1_i + f2_j); leakyrelu'd scores are bounded
// (|f1|,|f2| <~ 8) so raw exp() cannot overflow fp32 -> skip softmax max-shift.
// Masked entries get p=0, identical to reference's -1e12 fill.

#define N 8192
#define F 128
#define JS 4      // attention j-split (for occupancy); partial numerators reduced in k4
#define RT 128    // rows per attention block
#define TJ 32     // j tile

// ws layout (float elements):
//   Wh    [2][N][F]        @ 0          (2,097,152)
//   hpart [2][JS][N][F]    @ 2,097,152  (8,388,608)
//   f1    [2][N]           @ 10,485,760 (16,384)
//   f2    [2][N]           @ 10,502,144 (16,384)
//   Lpart [2][JS][N]       @ 10,518,528 (65,536)
//   qln   [F]              @ 10,584,064 (128)
// total 10,584,192 floats = 42.3 MB of ws

// ---------------- K1: Wh = X @ W for both layers ----------------
__global__ __launch_bounds__(128) void k1_wh(
    const float* __restrict__ X2, const float* __restrict__ W0,
    const float* __restrict__ W1, float* __restrict__ Wh) {
  const int l  = blockIdx.y;
  const int i0 = blockIdx.x * 16;
  const int c  = threadIdx.x;
  const float* __restrict__ X = X2 + (size_t)l * N * F + (size_t)i0 * F;
  const float* __restrict__ W = l ? W1 : W0;

  __shared__ __align__(16) float sX[16 * F];
  {
    const float4* src = (const float4*)X;
    float4* dst = (float4*)sX;
#pragma unroll
    for (int q = 0; q < 4; ++q) dst[q * 128 + c] = src[q * 128 + c];
  }
  __syncthreads();

  float acc[16];
#pragma unroll
  for (int r = 0; r < 16; ++r) acc[r] = 0.f;

  for (int f4 = 0; f4 < 32; ++f4) {
    float w0 = W[(f4 * 4 + 0) * F + c];
    float w1 = W[(f4 * 4 + 1) * F + c];
    float w2 = W[(f4 * 4 + 2) * F + c];
    float w3 = W[(f4 * 4 + 3) * F + c];
#pragma unroll
    for (int r = 0; r < 16; ++r) {
      float4 xv = *(const float4*)(&sX[r * F + f4 * 4]);
      acc[r] = fmaf(xv.x, w0, acc[r]);
      acc[r] = fmaf(xv.y, w1, acc[r]);
      acc[r] = fmaf(xv.z, w2, acc[r]);
      acc[r] = fmaf(xv.w, w3, acc[r]);
    }
  }
  float* out = Wh + (size_t)l * N * F + (size_t)i0 * F;
#pragma unroll
  for (int r = 0; r < 16; ++r) out[r * F + c] = acc[r];
}

// ---------------- K1b: f1 = Wh@a[:F], f2 = Wh@a[F:] (one wave per row) --------
__global__ __launch_bounds__(256) void k1b_f12(
    const float* __restrict__ Wh, const float* __restrict__ a0,
    const float* __restrict__ a1, float* __restrict__ f1g,
    float* __restrict__ f2g) {
  const int l = blockIdx.y;
  const int w = threadIdx.x >> 6, lane = threadIdx.x & 63;
  const int i = blockIdx.x * 4 + w;
  const float* __restrict__ a = l ? a1 : a0;
  const float* __restrict__ row = Wh + ((size_t)l * N + i) * F;
  float v1 = row[lane], v2 = row[64 + lane];
  float s1 = fmaf(v1, a[lane], v2 * a[64 + lane]);
  float s2 = fmaf(v1, a[128 + lane], v2 * a[192 + lane]);
#pragma unroll
  for (int off = 32; off; off >>= 1) {
    s1 += __shfl_down(s1, off);
    s2 += __shfl_down(s2, off);
  }
  if (lane == 0) {
    f1g[l * N + i] = s1;
    f2g[l * N + i] = s2;
  }
}

// ---------------- K3: layernorm of query [1,F] ----------------
__global__ __launch_bounds__(128) void k3_qln(
    const float* __restrict__ query, const float* __restrict__ gamma,
    const float* __restrict__ beta, float* __restrict__ qln) {
  const int t = threadIdx.x;
  float v = query[t];
  float s = v, sq = v * v;
#pragma unroll
  for (int off = 32; off; off >>= 1) {
    s += __shfl_down(s, off);
    sq += __shfl_down(sq, off);
  }
  __shared__ float sb[4];
  if ((t & 63) == 0) {
    sb[t >> 6] = s;
    sb[2 + (t >> 6)] = sq;
  }
  __syncthreads();
  float S = sb[0] + sb[1], SQ = sb[2] + sb[3];
  float mu = S * (1.f / 128.f);
  float var = SQ * (1.f / 128.f) - mu * mu;
  qln[t] = (v - mu) * rsqrtf(var + 1e-5f) * gamma[t] + beta[t];
}

// ---------------- K2: fused masked-softmax attention numerator ----------------
// hpart[l][s][i][:] = sum_{j in split s, adj} exp(leaky(f1_i+f2_j)) * Wh_j
// Lpart[l][s][i]    = sum_{j in split s, adj} exp(leaky(f1_i+f2_j))
#define FMA8(pq, A, B, k)                   \
  acc[k][0] = fmaf(pq, A.x, acc[k][0]);     \
  acc[k][1] = fmaf(pq, A.y, acc[k][1]);     \
  acc[k][2] = fmaf(pq, A.z, acc[k][2]);     \
  acc[k][3] = fmaf(pq, A.w, acc[k][3]);     \
  acc[k][4] = fmaf(pq, B.x, acc[k][4]);     \
  acc[k][5] = fmaf(pq, B.y, acc[k][5]);     \
  acc[k][6] = fmaf(pq, B.z, acc[k][6]);     \
  acc[k][7] = fmaf(pq, B.w, acc[k][7]);

__global__ __launch_bounds__(256) void k2_attn(
    const float* __restrict__ Wh, const float* __restrict__ f1g,
    const float* __restrict__ f2g, const int* __restrict__ adj,
    float* __restrict__ hpart, float* __restrict__ Lpart) {
  const int l  = blockIdx.y;
  const int s  = blockIdx.z;
  const int i0 = blockIdx.x * RT;
  const int t  = threadIdx.x;
  const int rg = t >> 4;    // 0..15 : rows rg*8..rg*8+7
  const int cg = t & 15;    // channel group: c0 = 8*cg
  const int c0 = cg * 8;

  __shared__ __align__(16) float sp[RT * TJ];   // p tile [r][jj]
  __shared__ __align__(16) float sWh[TJ * F];   // Wh tile [jj][c]
  __shared__ float sf1[RT];

  const float* __restrict__ WhL  = Wh + (size_t)l * N * F;
  const int* __restrict__ adjL   = adj + (size_t)l * N * N;
  const float* __restrict__ f2L  = f2g + l * N;

  if (t < RT) sf1[t] = f1g[l * N + i0 + t];

  float acc[8][8];
#pragma unroll
  for (int k = 0; k < 8; ++k)
#pragma unroll
    for (int u = 0; u < 8; ++u) acc[k][u] = 0.f;
  float Lacc[8];
#pragma unroll
  for (int k = 0; k < 8; ++k) Lacc[k] = 0.f;

  const int jjp = t & 31;  // p-phase column
  const int rb  = t >> 5;  // p-phase row base 0..7

  const int jbeg = s * (N / JS), jend = (s + 1) * (N / JS);
  for (int j0 = jbeg; j0 < jend; j0 += TJ) {
    __syncthreads();  // previous accumulate phase done reading LDS
    // stage Wh tile (32 rows x 128 ch)
    {
      const float4* src = (const float4*)(WhL + (size_t)j0 * F);
      float4* dst = (float4*)sWh;
#pragma unroll
      for (int q = 0; q < 4; ++q) dst[q * 256 + t] = src[q * 256 + t];
    }
    // p tile: 16 entries per thread, column jjp, rows k*8+rb
    {
      float f2v = f2L[j0 + jjp];
      int av[16];
#pragma unroll
      for (int k = 0; k < 16; ++k)
        av[k] = adjL[(size_t)(i0 + k * 8 + rb) * N + (j0 + jjp)];
#pragma unroll
      for (int k = 0; k < 16; ++k) {
        int r = k * 8 + rb;
        float sc = sf1[r] + f2v;
        sc = sc > 0.f ? sc : 0.2f * sc;
        sp[r * TJ + jjp] = av[k] ? __expf(sc) : 0.f;
      }
    }
    __syncthreads();
    // accumulate: 8x8 register tile, jj rotated per rg to spread LDS rows
    for (int jb = 0; jb < TJ; jb += 4) {
      const int jj = (jb + ((rg & 7) * 4)) & (TJ - 1);
      float4 wa[4], wb[4];
#pragma unroll
      for (int q = 0; q < 4; ++q) {
        const float* wr = &sWh[(jj + q) * F + c0];
        wa[q] = *(const float4*)wr;
        wb[q] = *(const float4*)(wr + 4);
      }
#pragma unroll
      for (int k = 0; k < 8; ++k) {
        float4 pv = *(const float4*)(&sp[(rg * 8 + k) * TJ + jj]);
        if (cg == 0) Lacc[k] += (pv.x + pv.y) + (pv.z + pv.w);
        FMA8(pv.x, wa[0], wb[0], k)
        FMA8(pv.y, wa[1], wb[1], k)
        FMA8(pv.z, wa[2], wb[2], k)
        FMA8(pv.w, wa[3], wb[3], k)
      }
    }
  }

  // epilogue: write partial numerator + partial row sums
  const size_t base = ((size_t)(l * JS + s) * N + i0) * F;
#pragma unroll
  for (int k = 0; k < 8; ++k) {
    const int r = rg * 8 + k;
    float4 o1 = make_float4(acc[k][0], acc[k][1], acc[k][2], acc[k][3]);
    float4 o2 = make_float4(acc[k][4], acc[k][5], acc[k][6], acc[k][7]);
    *(float4*)(hpart + base + (size_t)r * F + c0)     = o1;
    *(float4*)(hpart + base + (size_t)r * F + c0 + 4) = o2;
  }
  if (cg == 0) {
#pragma unroll
    for (int k = 0; k < 8; ++k)
      Lpart[(size_t)(l * JS + s) * N + i0 + rg * 8 + k] = Lacc[k];
  }
}

// ---------------- K4: combine partials, query attention, mix, residual -------
__device__ inline float blockRed128(float v, float* sb, int t) {
#pragma unroll
  for (int off = 32; off; off >>= 1) v += __shfl_down(v, off);
  __syncthreads();  // protect sb from previous round's readers
  if ((t & 63) == 0) sb[t >> 6] = v;
  __syncthreads();
  return sb[0] + sb[1];
}

__global__ __launch_bounds__(128) void k4_mix(
    const float* __restrict__ hpart, const float* __restrict__ Lpart,
    const float* __restrict__ MPNN, const float* __restrict__ qln,
    const float* __restrict__ x0, const float* __restrict__ res,
    float* __restrict__ out) {
  const int i = blockIdx.x;
  const int c = threadIdx.x;
  __shared__ float sb[2];

  float h0v = 0.f, h1v = 0.f, L0 = 0.f, L1 = 0.f;
#pragma unroll
  for (int sx = 0; sx < JS; ++sx) {
    h0v += hpart[((size_t)(0 * JS + sx) * N + i) * F + c];
    h1v += hpart[((size_t)(1 * JS + sx) * N + i) * F + c];
    L0  += Lpart[(size_t)(0 * JS + sx) * N + i];
    L1  += Lpart[(size_t)(1 * JS + sx) * N + i];
  }
  h0v /= L0;
  h1v /= L1;
  float mv = MPNN[(size_t)i * F + c];
  float qv = qln[c];
  float w1 = blockRed128(qv * h0v, sb, c);
  float w2 = blockRed128(qv * h1v, sb, c);
  float w3 = blockRed128(qv * mv, sb, c);
  float m  = fmaxf(w1, fmaxf(w2, w3));
  float e1 = __expf(w1 - m), e2 = __expf(w2 - m), e3 = __expf(w3 - m);
  float inv = 1.f / (e1 + e2 + e3);
  float mix = (e1 * h0v + e2 * h1v + e3 * mv) * inv;
  out[(size_t)i * F + c] = res[0] * mix + x0[(size_t)i * F + c];
}

extern "C" void kernel_launch(void* const* d_in, const int* in_sizes, int n_in,
                              void* d_out, int out_size, void* d_ws,
                              size_t ws_size, hipStream_t stream) {
  const float* x2    = (const float*)d_in[0];   // input_hs [2][N][F]
  const int*   adj   = (const int*)d_in[1];     // adjs [2][N][N] (bool->int32)
  const float* mpnn  = (const float*)d_in[2];   // [N][F]
  const float* query = (const float*)d_in[3];   // [1][F]
  const float* W0    = (const float*)d_in[4];
  const float* a0    = (const float*)d_in[5];
  const float* W1    = (const float*)d_in[6];
  const float* a1    = (const float*)d_in[7];
  const float* gamma = (const float*)d_in[8];
  const float* beta  = (const float*)d_in[9];
  const float* res   = (const float*)d_in[10];  // [1][1]

  float* ws    = (float*)d_ws;
  float* Wh    = ws;
  float* hpart = ws + 2097152;
  float* f1g   = ws + 10485760;
  float* f2g   = ws + 10502144;
  float* Lpart = ws + 10518528;
  float* qln   = ws + 10584064;
  float* out   = (float*)d_out;

  k1_wh<<<dim3(N / 16, 2), 128, 0, stream>>>(x2, W0, W1, Wh);
  k1b_f12<<<dim3(N / 4, 2), 256, 0, stream>>>(Wh, a0, a1, f1g, f2g);
  k3_qln<<<1, 128, 0, stream>>>(query, gamma, beta, qln);
  k2_attn<<<dim3(N / RT, 2, JS), 256, 0, stream>>>(Wh, f1g, f2g, adj, hpart,
                                                   Lpart);
  k4_mix<<<N, 128, 0, stream>>>(hpart, Lpart, mpnn, qln, x2, res, out);
}

// Round 2
// 783.857 us; speedup vs baseline: 1.5231x; 1.5231x over previous
//
#include <hip/hip_runtime.h>
#include <hip/hip_bf16.h>
#include <cstdint>

// MultiViewGAT: N=8192, F=128. Round 2: MFMA-based attention.
// k2 computes P (masked exp of rank-1 scores) in fp32, rounds to bf16 in LDS,
// and does P@Wh with mfma_f32_16x16x32_bf16. The softmax denominator is a
// ones-column B fragment of the SAME mfma -> numerator/denominator use
// identical bf16 weights, so the ratio cancels most quantization error.
// adj (bool->int32) streaming read of 512 MB is the HBM floor (~81 us).

#define N 8192
#define F 128
#define JS 4      // j-splits; partials reduced in k4
#define RT 128    // i-rows per k2 block
#define PSTR 40   // LDS row stride in bf16 (pad 32->40: 80B rows, 2-way banks = free)

typedef __attribute__((ext_vector_type(8))) short short8;
typedef __attribute__((ext_vector_type(8))) unsigned short ushort8;
typedef __attribute__((ext_vector_type(4))) float floatx4;

__device__ inline unsigned short f2bf(float x) {
  unsigned int u = __float_as_uint(x);
  u += 0x7FFFu + ((u >> 16) & 1u);   // RNE
  return (unsigned short)(u >> 16);
}

// ws layout (float elements):
//   Whbt  [2][F][N] bf16    @ 0          (1,048,576 float slots = 4 MB)
//   hpart [2][JS][N][F]     @ 1,048,576  (8,388,608)
//   f1    [2][N]            @ 9,437,184  (16,384)
//   f2    [2][N]            @ 9,453,568  (16,384)
//   Lpart [2][JS][N]        @ 9,469,952  (65,536)
//   qln   [F]               @ 9,535,488  (128)
// total 9,535,616 floats = 38.1 MB

// ---------------- K1: Wh = X @ W; emit bf16 Whbt (transposed) + f1/f2 -------
__global__ __launch_bounds__(128) void k1_wh(
    const float* __restrict__ X2, const float* __restrict__ W0,
    const float* __restrict__ W1, const float* __restrict__ a0,
    const float* __restrict__ a1, unsigned short* __restrict__ Whbt,
    float* __restrict__ f1g, float* __restrict__ f2g) {
  const int l  = blockIdx.y;
  const int i0 = blockIdx.x * 16;
  const int c  = threadIdx.x;
  const float* __restrict__ X = X2 + (size_t)l * N * F + (size_t)i0 * F;
  const float* __restrict__ W = l ? W1 : W0;

  __shared__ __align__(16) float sX[16 * F];
  __shared__ float red[2][2][16];
  {
    const float4* src = (const float4*)X;
    float4* dst = (float4*)sX;
#pragma unroll
    for (int qq = 0; qq < 4; ++qq) dst[qq * 128 + c] = src[qq * 128 + c];
  }
  __syncthreads();

  float acc[16];
#pragma unroll
  for (int r = 0; r < 16; ++r) acc[r] = 0.f;

  for (int f4 = 0; f4 < 32; ++f4) {
    float w0 = W[(f4 * 4 + 0) * F + c];
    float w1 = W[(f4 * 4 + 1) * F + c];
    float w2 = W[(f4 * 4 + 2) * F + c];
    float w3 = W[(f4 * 4 + 3) * F + c];
#pragma unroll
    for (int r = 0; r < 16; ++r) {
      float4 xv = *(const float4*)(&sX[r * F + f4 * 4]);
      acc[r] = fmaf(xv.x, w0, acc[r]);
      acc[r] = fmaf(xv.y, w1, acc[r]);
      acc[r] = fmaf(xv.z, w2, acc[r]);
      acc[r] = fmaf(xv.w, w3, acc[r]);
    }
  }

  // Whbt[l][c][i0..i0+16) bf16
  {
    unsigned short* wdst = Whbt + (size_t)l * F * N + (size_t)c * N + i0;
    ushort8 u0, u1;
#pragma unroll
    for (int r = 0; r < 8; ++r) {
      u0[r] = f2bf(acc[r]);
      u1[r] = f2bf(acc[8 + r]);
    }
    *(ushort8*)wdst = u0;
    *(ushort8*)(wdst + 8) = u1;
  }

  // f1/f2: reduce acc[r]*a[c] over 128 channels
  const float* __restrict__ a = l ? a1 : a0;
  const float a1c = a[c], a2c = a[F + c];
  const int w = c >> 6, lane = c & 63;
#pragma unroll
  for (int r = 0; r < 16; ++r) {
    float s1 = acc[r] * a1c;
    float s2 = acc[r] * a2c;
#pragma unroll
    for (int off = 32; off; off >>= 1) {
      s1 += __shfl_down(s1, off);
      s2 += __shfl_down(s2, off);
    }
    if (lane == 0) {
      red[w][0][r] = s1;
      red[w][1][r] = s2;
    }
  }
  __syncthreads();
  if (c < 16)
    f1g[l * N + i0 + c] = red[0][0][c] + red[1][0][c];
  else if (c < 32)
    f2g[l * N + i0 + c - 16] = red[0][1][c - 16] + red[1][1][c - 16];
}

// ---------------- K3: layernorm of query [1,F] ----------------
__global__ __launch_bounds__(128) void k3_qln(
    const float* __restrict__ query, const float* __restrict__ gamma,
    const float* __restrict__ beta, float* __restrict__ qln) {
  const int t = threadIdx.x;
  float v = query[t];
  float s = v, sq = v * v;
#pragma unroll
  for (int off = 32; off; off >>= 1) {
    s += __shfl_down(s, off);
    sq += __shfl_down(sq, off);
  }
  __shared__ float sb[4];
  if ((t & 63) == 0) {
    sb[t >> 6] = s;
    sb[2 + (t >> 6)] = sq;
  }
  __syncthreads();
  float S = sb[0] + sb[1], SQ = sb[2] + sb[3];
  float mu = S * (1.f / 128.f);
  float var = SQ * (1.f / 128.f) - mu * mu;
  qln[t] = (v - mu) * rsqrtf(var + 1e-5f) * gamma[t] + beta[t];
}

// ---------------- K2: MFMA masked-softmax attention (numerator + denom) ------
// Per block: 128 i-rows x 128 channels, j-range N/JS, K-tile 32.
// A = P[128 x 32] bf16 (LDS, row-major stride PSTR)
// B = Wh[32 x 128] bf16 (LDS, channel-major stride PSTR, j contiguous)
// extra B "ones column" tile accumulates row sums (softmax denominator).
__global__ __launch_bounds__(256) void k2_attn(
    const unsigned short* __restrict__ Whbt, const float* __restrict__ f1g,
    const float* __restrict__ f2g, const int* __restrict__ adj,
    float* __restrict__ hpart, float* __restrict__ Lpart) {
  const int l  = blockIdx.y;
  const int s  = blockIdx.z;
  const int i0 = blockIdx.x * RT;
  const int t  = threadIdx.x;
  const int wave = t >> 6;
  const int lane = t & 63;
  const int lpos = lane & 15;   // C/D col, A row, B col
  const int halfk = lane >> 4;  // k-offset group: k = halfk*8 + {0..7}

  // P-compute mapping: 16 entries/thread = 4 rows x 4 j
  const int q  = t & 7;   // j-group (4 j each)
  const int r0 = t >> 3;  // row 0..31 (rows r0 + 32*rp)

  __shared__ __align__(16) unsigned short sP[RT * PSTR];  // 10 KB
  __shared__ __align__(16) unsigned short sB[F * PSTR];   // 10 KB

  const unsigned short* __restrict__ WhbL = Whbt + (size_t)l * F * N;
  const int* __restrict__ adjL = adj + (size_t)l * N * N;
  const float* __restrict__ f2L = f2g + l * N;

  float f1v[4];
  const int* adjR[4];
#pragma unroll
  for (int rp = 0; rp < 4; ++rp) {
    f1v[rp] = f1g[l * N + i0 + r0 + 32 * rp];
    adjR[rp] = adjL + (size_t)(i0 + r0 + 32 * rp) * N;
  }
  const unsigned short* wsrc0 = WhbL + (size_t)(t >> 1) * N + (t & 1) * 16;
  const int sBoff = (t >> 1) * PSTR + (t & 1) * 16;

  floatx4 acc[2][9];
#pragma unroll
  for (int mt = 0; mt < 2; ++mt)
#pragma unroll
    for (int nt = 0; nt < 9; ++nt) acc[mt][nt] = (floatx4){0.f, 0.f, 0.f, 0.f};

  short8 ones;
  {
    short v = (lpos == 0) ? (short)0x3F80 : (short)0;  // bf16 1.0
#pragma unroll
    for (int e = 0; e < 8; ++e) ones[e] = v;
  }

  const int jbeg = s * (N / JS), jend = (s + 1) * (N / JS);
  for (int j0 = jbeg; j0 < jend; j0 += 32) {
    // ---- global loads (independent of LDS) ----
    uint4 wv0 = *(const uint4*)(wsrc0 + j0);
    uint4 wv1 = *(const uint4*)(wsrc0 + j0 + 8);
    float4 f2v = *(const float4*)(f2L + j0 + 4 * q);
    int4 av[4];
#pragma unroll
    for (int rp = 0; rp < 4; ++rp) av[rp] = *(const int4*)(adjR[rp] + j0 + 4 * q);

    // ---- compute P entries (fp32 -> bf16 packed) ----
    uint2 pk[4];
#pragma unroll
    for (int rp = 0; rp < 4; ++rp) {
      float b = f1v[rp];
      float s0 = b + f2v.x, s1 = b + f2v.y, s2 = b + f2v.z, s3 = b + f2v.w;
      s0 = fmaxf(s0, 0.2f * s0);
      s1 = fmaxf(s1, 0.2f * s1);
      s2 = fmaxf(s2, 0.2f * s2);
      s3 = fmaxf(s3, 0.2f * s3);
      float p0 = av[rp].x ? __expf(s0) : 0.f;
      float p1 = av[rp].y ? __expf(s1) : 0.f;
      float p2 = av[rp].z ? __expf(s2) : 0.f;
      float p3 = av[rp].w ? __expf(s3) : 0.f;
      pk[rp].x = (unsigned int)f2bf(p0) | ((unsigned int)f2bf(p1) << 16);
      pk[rp].y = (unsigned int)f2bf(p2) | ((unsigned int)f2bf(p3) << 16);
    }

    __syncthreads();  // previous iteration's MFMA reads done
    // ---- LDS writes ----
    *(uint4*)&sB[sBoff] = wv0;
    *(uint4*)&sB[sBoff + 8] = wv1;
#pragma unroll
    for (int rp = 0; rp < 4; ++rp)
      *(uint2*)&sP[(r0 + 32 * rp) * PSTR + 4 * q] = pk[rp];
    __syncthreads();

    // ---- fragments + MFMA ----
    short8 af[2];
#pragma unroll
    for (int mt = 0; mt < 2; ++mt)
      af[mt] = *(const short8*)&sP[(wave * 32 + mt * 16 + lpos) * PSTR + halfk * 8];
#pragma unroll
    for (int nt = 0; nt < 8; ++nt) {
      short8 bf = *(const short8*)&sB[(nt * 16 + lpos) * PSTR + halfk * 8];
      acc[0][nt] = __builtin_amdgcn_mfma_f32_16x16x32_bf16(af[0], bf, acc[0][nt], 0, 0, 0);
      acc[1][nt] = __builtin_amdgcn_mfma_f32_16x16x32_bf16(af[1], bf, acc[1][nt], 0, 0, 0);
    }
    acc[0][8] = __builtin_amdgcn_mfma_f32_16x16x32_bf16(af[0], ones, acc[0][8], 0, 0, 0);
    acc[1][8] = __builtin_amdgcn_mfma_f32_16x16x32_bf16(af[1], ones, acc[1][8], 0, 0, 0);
  }

  // ---- epilogue: partial numerator + partial denominators ----
  const size_t obase = ((size_t)(l * JS + s) * N + i0) * F;
  const size_t lbase = (size_t)(l * JS + s) * N + i0;
#pragma unroll
  for (int mt = 0; mt < 2; ++mt) {
    const int rb = wave * 32 + mt * 16 + halfk * 4;  // C/D: row=(lane>>4)*4+reg
#pragma unroll
    for (int nt = 0; nt < 8; ++nt) {
#pragma unroll
      for (int reg = 0; reg < 4; ++reg)
        hpart[obase + (size_t)(rb + reg) * F + nt * 16 + lpos] = acc[mt][nt][reg];
    }
    if (lpos == 0) {
#pragma unroll
      for (int reg = 0; reg < 4; ++reg)
        Lpart[lbase + rb + reg] = acc[mt][8][reg];
    }
  }
}

// ---------------- K4: combine partials, query attention, mix, residual -------
// one wave per row; 2 channels per lane; shuffle-only reductions.
__global__ __launch_bounds__(256) void k4_mix(
    const float* __restrict__ hpart, const float* __restrict__ Lpart,
    const float* __restrict__ MPNN, const float* __restrict__ qln,
    const float* __restrict__ x0, const float* __restrict__ res,
    float* __restrict__ out) {
  const int row  = blockIdx.x * 4 + (threadIdx.x >> 6);
  const int lane = threadIdx.x & 63;
  const int c    = lane * 2;

  float h0x = 0.f, h0y = 0.f, h1x = 0.f, h1y = 0.f, L0 = 0.f, L1 = 0.f;
#pragma unroll
  for (int sx = 0; sx < JS; ++sx) {
    float2 v0 = *(const float2*)&hpart[((size_t)(0 * JS + sx) * N + row) * F + c];
    float2 v1 = *(const float2*)&hpart[((size_t)(1 * JS + sx) * N + row) * F + c];
    h0x += v0.x; h0y += v0.y;
    h1x += v1.x; h1y += v1.y;
    L0 += Lpart[(size_t)(0 * JS + sx) * N + row];
    L1 += Lpart[(size_t)(1 * JS + sx) * N + row];
  }
  const float i0v = 1.f / L0, i1v = 1.f / L1;
  h0x *= i0v; h0y *= i0v;
  h1x *= i1v; h1y *= i1v;

  float2 mv = *(const float2*)&MPNN[(size_t)row * F + c];
  float2 qv = *(const float2*)&qln[c];
  float w1 = qv.x * h0x + qv.y * h0y;
  float w2 = qv.x * h1x + qv.y * h1y;
  float w3 = qv.x * mv.x + qv.y * mv.y;
#pragma unroll
  for (int off = 1; off < 64; off <<= 1) {
    w1 += __shfl_xor(w1, off);
    w2 += __shfl_xor(w2, off);
    w3 += __shfl_xor(w3, off);
  }
  float m = fmaxf(w1, fmaxf(w2, w3));
  float e1 = __expf(w1 - m), e2 = __expf(w2 - m), e3 = __expf(w3 - m);
  float inv = res[0] / (e1 + e2 + e3);
  float2 xr = *(const float2*)&x0[(size_t)row * F + c];
  float2 o;
  o.x = (e1 * h0x + e2 * h1x + e3 * mv.x) * inv + xr.x;
  o.y = (e1 * h0y + e2 * h1y + e3 * mv.y) * inv + xr.y;
  *(float2*)&out[(size_t)row * F + c] = o;
}

extern "C" void kernel_launch(void* const* d_in, const int* in_sizes, int n_in,
                              void* d_out, int out_size, void* d_ws,
                              size_t ws_size, hipStream_t stream) {
  const float* x2    = (const float*)d_in[0];   // input_hs [2][N][F]
  const int*   adj   = (const int*)d_in[1];     // adjs [2][N][N] (bool->int32)
  const float* mpnn  = (const float*)d_in[2];   // [N][F]
  const float* query = (const float*)d_in[3];   // [1][F]
  const float* W0    = (const float*)d_in[4];
  const float* a0    = (const float*)d_in[5];
  const float* W1    = (const float*)d_in[6];
  const float* a1    = (const float*)d_in[7];
  const float* gamma = (const float*)d_in[8];
  const float* beta  = (const float*)d_in[9];
  const float* res   = (const float*)d_in[10];  // [1][1]

  float* ws = (float*)d_ws;
  unsigned short* Whbt = (unsigned short*)ws;        // 4 MB
  float* hpart = ws + 1048576;
  float* f1g   = ws + 9437184;
  float* f2g   = ws + 9453568;
  float* Lpart = ws + 9469952;
  float* qln   = ws + 9535488;
  float* out   = (float*)d_out;

  k1_wh<<<dim3(N / 16, 2), 128, 0, stream>>>(x2, W0, W1, a0, a1, Whbt, f1g, f2g);
  k3_qln<<<1, 128, 0, stream>>>(query, gamma, beta, qln);
  k2_attn<<<dim3(N / RT, 2, JS), 256, 0, stream>>>(Whbt, f1g, f2g, adj, hpart,
                                                   Lpart);
  k4_mix<<<N / 4, 256, 0, stream>>>(hpart, Lpart, mpnn, qln, x2, res, out);
}